// Round 1
// baseline (188.143 us; speedup 1.0000x reference)
//
#include <hip/hip_runtime.h>
#include <hip/hip_bf16.h>

// ModulatedConv2d: out = oscale[b,co] * conv2d(s[b,ci]*x, w_bf16)
// B=8, C=512, K=3, H=W=64.

#define BDIM 8
#define CDIM 512
#define HW 64
#define CK 32
#define NCHUNK 16   // 512/32

typedef __attribute__((ext_vector_type(8))) short short8;
typedef __attribute__((ext_vector_type(4))) float float4v;

__device__ __forceinline__ short f2bf(float f) {
    unsigned u = __float_as_uint(f);
    unsigned r = (u + 0x7FFFu + ((u >> 16) & 1u)) >> 16;
    return (short)r;
}

__device__ __forceinline__ void async_ld16(const short* g, short* l) {
    __builtin_amdgcn_global_load_lds(
        (const __attribute__((address_space(1))) void*)g,
        (__attribute__((address_space(3))) void*)l, 16, 0, 0);
}

// ---------------- prep kernels ----------------

// s[b][ci] = style[b,:] . affine_w[ci,:] * (1/sqrt(512)) + affine_b[ci]
__global__ void k_affine(const float* __restrict__ style, const float* __restrict__ aw,
                         const float* __restrict__ ab, float* __restrict__ s) {
    int b = blockIdx.x;
    int ci = blockIdx.y * 256 + threadIdx.x;
    const float* st = style + b * CDIM;
    const float* w = aw + ci * CDIM;
    float acc = 0.f;
    for (int k = 0; k < CDIM; ++k) acc += st[k] * w[k];
    s[b * CDIM + ci] = acc * 0.04419417382415922f + ab[ci];
}

// ws2[co*512+ci] = sum_t w[co,ci,t]^2
__global__ void k_ws2(const float* __restrict__ w, float* __restrict__ ws2) {
    int i = blockIdx.x * 256 + threadIdx.x;  // 262144
    const float* p = w + i * 9;
    float a = 0.f;
#pragma unroll
    for (int t = 0; t < 9; ++t) a += p[t] * p[t];
    ws2[i] = a;
}

// oscale[b][co] = wg * rsqrt(wg^2 * sum_ci s^2*ws2 + 1e-8)
__global__ void k_oscale(const float* __restrict__ s, const float* __restrict__ ws2,
                         float* __restrict__ osc) {
    __shared__ float s2[CDIM];
    int b = blockIdx.x;
    int co = blockIdx.y * 256 + threadIdx.x;
    for (int i = threadIdx.x; i < CDIM; i += 256) {
        float v = s[b * CDIM + i];
        s2[i] = v * v;
    }
    __syncthreads();
    const float* r = ws2 + co * CDIM;
    float acc = 0.f;
    for (int k = 0; k < CDIM; ++k) acc += s2[k] * r[k];
    const float wg = 0.014731391274719739f;          // 1/sqrt(4608)
    const float wg2 = 2.170138888888889e-4f;         // 1/4608
    osc[b * CDIM + co] = wg * rsqrtf(wg2 * acc + 1e-8f);
}

// Wg[chunk(16)][ct(4)][t(9)][co_l(128)][ci_l(32)] bf16, from w[co][ci][t] fp32
__global__ void k_wconv(const float* __restrict__ w, short* __restrict__ wgt) {
    int idx = blockIdx.x * 256 + threadIdx.x;  // 2359296
    int cil = idx & 31;
    int r = idx >> 5;
    int colL = r & 127; r >>= 7;
    int t = r % 9; r /= 9;
    int ct = r & 3;
    int c = r >> 2;
    int co = ct * 128 + colL;
    int ci = c * 32 + cil;
    wgt[idx] = f2bf(w[(co * CDIM + ci) * 9 + t]);
}

// ---------------- main conv ----------------
// grid 512 blocks x 512 threads. Block: (b, row-tile of 4, co-tile of 128).
__global__ __launch_bounds__(512, 2) void conv_main(
    const float* __restrict__ x, const float* __restrict__ s,
    const short* __restrict__ wgt, const float* __restrict__ osc,
    float* __restrict__ out) {

    __shared__ __align__(16) short w_lds[9 * 128 * CK];     // 73728 B
    __shared__ __align__(16) short x_lds[2][6 * 66 * CK];   // 2*25344 B

    const int tid = threadIdx.x;
    const int lane = tid & 63;
    const int wid = tid >> 6;
    const int wm = wid >> 2;   // 0..1  (co half)
    const int wn = wid & 3;    // 0..3  (output row in tile / col-quarter in staging)
    const int l15 = lane & 15;
    const int l4 = lane >> 4;

    // XCD-aware mapping: 4 co-tiles of the same (b, row-tile) land on one XCD.
    const int bx = blockIdx.x;
    const int xcd = bx & 7;
    const int ct = (bx >> 3) & 3;
    const int gh = bx >> 5;          // 0..15
    const int g = gh * 8 + xcd;      // 0..127
    const int b = g & 7;
    const int rt = g >> 3;           // 0..15
    const int r0 = rt * 4;

    // staging lane mapping
    const int cig = lane & 3;             // ci 8-block
    const int col = wn * 16 + (lane >> 2); // 0..63

    // zero halo columns (lcol 0 and 65) of both buffers, once
    for (int i = tid; i < 768; i += 512) {
        int bufi = i >= 384;
        int rem = i - bufi * 384;
        int rr = rem >> 6;
        int rem2 = rem & 63;
        int cc = (rem2 >= 32) ? 65 : 0;
        int cidx = rem2 & 31;
        x_lds[bufi][(rr * 66 + cc) * CK + cidx] = 0;
    }

    float rx[24];
    float sv[8];

    auto stage_w = [&](int c) {
        const short* src = wgt + (c * 4 + ct) * (9 * 128 * CK);
#pragma unroll
        for (int k = 0; k < 9; ++k) {
            int off = (k * 512 + wid * 64) * 8;   // shorts, wave-uniform
            async_ld16(src + off + lane * 8, w_lds + off);
        }
    };

    auto stage_x_load = [&](int c) {
#pragma unroll
        for (int j = 0; j < 8; ++j) sv[j] = s[b * CDIM + c * 32 + cig * 8 + j];
#pragma unroll
        for (int i = 0; i < 3; ++i) {
            int row = wm + i * 2;          // 0..5
            int grow = r0 - 1 + row;
            bool ok = (grow >= 0) && (grow < HW);
            int growc = ok ? grow : 0;
            const float* base = x + ((b * CDIM + c * 32 + cig * 8) * HW + growc) * HW + col;
#pragma unroll
            for (int j = 0; j < 8; ++j) {
                float v = base[j * (HW * HW)];
                rx[i * 8 + j] = ok ? v : 0.0f;
            }
        }
    };

    auto stage_x_write = [&](int buf) {
        int lcol = 1 + col;
        int qs = (cig ^ (lcol & 3)) * 8;
#pragma unroll
        for (int i = 0; i < 3; ++i) {
            int row = wm + i * 2;
            short8 pk;
#pragma unroll
            for (int j = 0; j < 8; ++j) pk[j] = f2bf(rx[i * 8 + j] * sv[j]);
            *(short8*)&x_lds[buf][(row * 66 + lcol) * CK + qs] = pk;
        }
    };

    float4v acc[4][4] = {};

    auto compute = [&](int buf) {
        const short* xb = x_lds[buf];
#pragma unroll
        for (int dh = -1; dh <= 1; ++dh) {
            int lrow = wn + dh + 1;   // 0..5
#pragma unroll
            for (int dw = -1; dw <= 1; ++dw) {
                int t = (dh + 1) * 3 + (dw + 1);
                short8 a[4], bf[4];
#pragma unroll
                for (int mf = 0; mf < 4; ++mf)
                    a[mf] = *(const short8*)&w_lds[(t * 128 + wm * 64 + mf * 16 + l15) * CK + l4 * 8];
                int cb = 1 + dw + l15;
                int xq = (l4 ^ (cb & 3)) * 8;
#pragma unroll
                for (int nf = 0; nf < 4; ++nf)
                    bf[nf] = *(const short8*)&xb[(lrow * 66 + cb + nf * 16) * CK + xq];
#pragma unroll
                for (int mf = 0; mf < 4; ++mf)
#pragma unroll
                    for (int nf = 0; nf < 4; ++nf)
                        acc[mf][nf] = __builtin_amdgcn_mfma_f32_16x16x32_bf16(
                            a[mf], bf[nf], acc[mf][nf], 0, 0, 0);
            }
        }
    };

    // prologue
    stage_w(0);
    stage_x_load(0);
    stage_x_write(0);
    __syncthreads();

    int cur = 0;
    for (int c = 0; c < NCHUNK; ++c) {
        if (c + 1 < NCHUNK) stage_x_load(c + 1);   // issue early, hide under MFMA
        compute(cur);
        if (c + 1 < NCHUNK) {
            __syncthreads();                        // all done with w_lds & x_lds[cur^1]
            stage_w(c + 1);                         // async global->LDS
            stage_x_write(cur ^ 1);                 // modulate + bf16 + ds_write
            __syncthreads();                        // full drain (vmcnt+lgkm)
            cur ^= 1;
        }
    }

    // epilogue: demodulate + store
    const int row_out = r0 + wn;
#pragma unroll
    for (int mf = 0; mf < 4; ++mf) {
#pragma unroll
        for (int j = 0; j < 4; ++j) {
            int co = ct * 128 + wm * 64 + mf * 16 + l4 * 4 + j;
            float oscv = osc[b * CDIM + co];
            float* po = out + ((b * CDIM + co) * HW + row_out) * HW;
#pragma unroll
            for (int nf = 0; nf < 4; ++nf)
                po[nf * 16 + l15] = acc[mf][nf][j] * oscv;
        }
    }
}

// ---------------- launcher ----------------

extern "C" void kernel_launch(void* const* d_in, const int* in_sizes, int n_in,
                              void* d_out, int out_size, void* d_ws, size_t ws_size,
                              hipStream_t stream) {
    const float* x     = (const float*)d_in[0];   // 8*512*64*64
    const float* style = (const float*)d_in[1];   // 8*512
    const float* w     = (const float*)d_in[2];   // 512*512*9
    const float* aw    = (const float*)d_in[3];   // 512*512
    const float* ab    = (const float*)d_in[4];   // 512
    float* out = (float*)d_out;

    float* s_buf = (float*)d_ws;                 // 4096
    float* ws2   = s_buf + 4096;                 // 262144
    float* osc   = ws2 + 262144;                 // 4096
    short* wgt   = (short*)(osc + 4096);         // 2359296 shorts (~4.5 MB)

    k_affine<<<dim3(8, 2), 256, 0, stream>>>(style, aw, ab, s_buf);
    k_ws2<<<1024, 256, 0, stream>>>(w, ws2);
    k_wconv<<<9216, 256, 0, stream>>>(w, wgt);
    k_oscale<<<dim3(8, 2), 256, 0, stream>>>(s_buf, ws2, osc);
    conv_main<<<512, 512, 0, stream>>>(x, s_buf, wgt, osc, out);
}